// Round 1
// baseline (84.239 us; speedup 1.0000x reference)
//
#include <hip/hip_runtime.h>

// Chamfer distance, B=4, N=M=8192, D=3, fp32.
// Strategy:
//   Pass 1 (chamfer_min): brute-force all pairs, both directions.
//     grid = 256 blocks = 2(dir) x 4(batch) x 4(query chunk of 2048) x 8(target chunk of 1024)
//     Each block stages its 1024-target chunk into LDS as float4 (x,y,z, 0.5*|t|^2),
//     each thread owns P=8 query points and tracks min of (0.5|t|^2 - q.t) -> 4 VALU/pair.
//     Partial minima combined across target chunks via atomicMin on order-encoded uint32.
//   Pass 2 (chamfer_loss): per query slot, dist^2 = 2*min + |q|^2; block-reduce to partials.
//   Pass 3 (chamfer_final): deterministic sum of 256 partials -> d_out[0].

#define NPTS    8192
#define BATCH   4
#define P       8
#define JT      1024
#define THREADS 256
#define NSLOTS  (2 * BATCH * NPTS)   // 65536

__device__ __forceinline__ unsigned int enc_f32(float f) {
  unsigned int u = __float_as_uint(f);
  return (u & 0x80000000u) ? ~u : (u | 0x80000000u);
}
__device__ __forceinline__ float dec_f32(unsigned int u) {
  u = (u & 0x80000000u) ? (u ^ 0x80000000u) : ~u;
  return __uint_as_float(u);
}

__global__ __launch_bounds__(256) void init_min(unsigned int* __restrict__ minbuf) {
  int i = blockIdx.x * 256 + threadIdx.x;
  if (i < NSLOTS) minbuf[i] = 0xFFFFFFFFu;  // decodes to +max
}

__global__ __launch_bounds__(THREADS) void chamfer_min(
    const float* __restrict__ c1, const float* __restrict__ c2,
    unsigned int* __restrict__ minbuf) {
  int bid = blockIdx.x;
  int dir = bid >> 7;          // 0: queries from c1, targets c2; 1: swapped
  int b   = (bid >> 5) & 3;    // batch
  int qc  = (bid >> 3) & 3;    // query chunk (2048 queries each)
  int jc  = bid & 7;           // target chunk (1024 targets each)

  const float* Q = dir ? c2 : c1;
  const float* T = dir ? c1 : c2;
  const float* Tb = T + ((size_t)b * NPTS + (size_t)jc * JT) * 3;
  const float* Qb = Q + (size_t)b * NPTS * 3;

  __shared__ float4 sT[JT];   // 16 KB
  int tid = threadIdx.x;
  #pragma unroll
  for (int s = 0; s < JT / THREADS; ++s) {
    int j = tid + s * THREADS;
    float x = Tb[j * 3 + 0];
    float y = Tb[j * 3 + 1];
    float z = Tb[j * 3 + 2];
    sT[j] = make_float4(x, y, z, 0.5f * (x * x + y * y + z * z));
  }
  __syncthreads();

  int q0 = qc * (THREADS * P);
  float qx[P], qy[P], qz[P], m[P];
  #pragma unroll
  for (int k = 0; k < P; ++k) {
    int qi = q0 + k * THREADS + tid;
    qx[k] = Qb[qi * 3 + 0];
    qy[k] = Qb[qi * 3 + 1];
    qz[k] = Qb[qi * 3 + 2];
    m[k] = 3.4e38f;
  }

  #pragma unroll 4
  for (int j = 0; j < JT; ++j) {
    float4 t = sT[j];   // uniform address -> LDS broadcast
    #pragma unroll
    for (int k = 0; k < P; ++k) {
      float r = fmaf(-qx[k], t.x, t.w);   // 0.5|t|^2 - qx*tx
      r = fmaf(-qy[k], t.y, r);
      r = fmaf(-qz[k], t.z, r);
      m[k] = fminf(m[k], r);
    }
  }

  unsigned int* mb = minbuf + ((size_t)dir * BATCH + b) * NPTS + q0;
  #pragma unroll
  for (int k = 0; k < P; ++k) {
    atomicMin(mb + k * THREADS + tid, enc_f32(m[k]));
  }
}

__global__ __launch_bounds__(256) void chamfer_loss(
    const float* __restrict__ c1, const float* __restrict__ c2,
    const unsigned int* __restrict__ minbuf, float* __restrict__ partials) {
  int slot = blockIdx.x * 256 + threadIdx.x;
  int dir = slot >> 15;
  int b   = (slot >> 13) & 3;
  int i   = slot & (NPTS - 1);
  const float* Q = dir ? c2 : c1;
  const float* q = Q + ((size_t)b * NPTS + i) * 3;
  float x = q[0], y = q[1], z = q[2];
  float qq = x * x + y * y + z * z;
  float v = dec_f32(minbuf[slot]);
  float d2 = fmaf(2.0f, v, qq);   // = |q|^2 + |t*|^2 - 2 q.t*

  // block reduction (deterministic)
  float s = d2;
  #pragma unroll
  for (int off = 32; off > 0; off >>= 1) s += __shfl_down(s, off, 64);
  __shared__ float wsum[4];
  if ((threadIdx.x & 63) == 0) wsum[threadIdx.x >> 6] = s;
  __syncthreads();
  if (threadIdx.x == 0)
    partials[blockIdx.x] = (wsum[0] + wsum[1]) + (wsum[2] + wsum[3]);
}

__global__ __launch_bounds__(256) void chamfer_final(
    const float* __restrict__ partials, float* __restrict__ out) {
  float s = partials[threadIdx.x];  // 256 partials, 256 threads
  #pragma unroll
  for (int off = 32; off > 0; off >>= 1) s += __shfl_down(s, off, 64);
  __shared__ float wsum[4];
  if ((threadIdx.x & 63) == 0) wsum[threadIdx.x >> 6] = s;
  __syncthreads();
  if (threadIdx.x == 0) out[0] = (wsum[0] + wsum[1]) + (wsum[2] + wsum[3]);
}

extern "C" void kernel_launch(void* const* d_in, const int* in_sizes, int n_in,
                              void* d_out, int out_size, void* d_ws, size_t ws_size,
                              hipStream_t stream) {
  const float* c1 = (const float*)d_in[0];
  const float* c2 = (const float*)d_in[1];
  float* out = (float*)d_out;

  unsigned int* minbuf = (unsigned int*)d_ws;                       // 65536 * 4 B
  float* partials = (float*)((char*)d_ws + (size_t)NSLOTS * 4);     // 256 * 4 B

  init_min<<<NSLOTS / 256, 256, 0, stream>>>(minbuf);
  chamfer_min<<<256, THREADS, 0, stream>>>(c1, c2, minbuf);
  chamfer_loss<<<NSLOTS / 256, 256, 0, stream>>>(c1, c2, minbuf, partials);
  chamfer_final<<<1, 256, 0, stream>>>(partials, out);
}

// Round 2
// 53.308 us; speedup vs baseline: 1.5802x; 1.5802x over previous
//
#include <hip/hip_runtime.h>

// Chamfer distance, B=4, N=M=8192, D=3, fp32.
//   Pass 1 (chamfer_min): brute-force all pairs, both directions.
//     grid = 1024 blocks = 2(dir) x 4(batch) x 4(qchunk of 2048) x 32(jchunk of 256)
//     -> 4 blocks/CU = 4 waves/SIMD (round-1 showed 1 wave/SIMD = 56% VALUBusy).
//     Block stages its 256-target chunk into LDS as float4 (x,y,z, 0.5*|t|^2);
//     each thread owns P=8 queries, tracks min of (0.5|t|^2 - q.t): 3 fma + min3/2.
//     Partial minima across jchunks combined via atomicMin on order-encoded u32.
//   Pass 2 (chamfer_loss): dist^2 = 2*min + |q|^2; block-reduce to partials.
//   Pass 3 (chamfer_final): deterministic sum of 256 partials -> d_out[0].

#define NPTS    8192
#define BATCH   4
#define P       8
#define JT      256
#define NJC     32
#define THREADS 256
#define NSLOTS  (2 * BATCH * NPTS)   // 65536

__device__ __forceinline__ unsigned int enc_f32(float f) {
  unsigned int u = __float_as_uint(f);
  return (u & 0x80000000u) ? ~u : (u | 0x80000000u);
}
__device__ __forceinline__ float dec_f32(unsigned int u) {
  u = (u & 0x80000000u) ? (u ^ 0x80000000u) : ~u;
  return __uint_as_float(u);
}

__global__ __launch_bounds__(256) void init_min(unsigned int* __restrict__ minbuf) {
  int i = blockIdx.x * 256 + threadIdx.x;
  if (i < NSLOTS) minbuf[i] = 0xFFFFFFFFu;  // decodes to +max
}

__global__ __launch_bounds__(THREADS, 4) void chamfer_min(
    const float* __restrict__ c1, const float* __restrict__ c2,
    unsigned int* __restrict__ minbuf) {
  int bid = blockIdx.x;
  int dir = bid >> 9;          // 0: queries c1 -> targets c2; 1: swapped
  int b   = (bid >> 7) & 3;    // batch
  int qc  = (bid >> 5) & 3;    // query chunk (2048 queries)
  int jc  = bid & (NJC - 1);   // target chunk (256 targets)

  const float* Q = dir ? c2 : c1;
  const float* T = dir ? c1 : c2;
  const float* Tb = T + ((size_t)b * NPTS + (size_t)jc * JT) * 3;
  const float* Qb = Q + (size_t)b * NPTS * 3;

  __shared__ float4 sT[JT];   // 4 KB
  int tid = threadIdx.x;
  {
    float x = Tb[tid * 3 + 0];
    float y = Tb[tid * 3 + 1];
    float z = Tb[tid * 3 + 2];
    sT[tid] = make_float4(x, y, z, 0.5f * (x * x + y * y + z * z));
  }
  __syncthreads();

  int q0 = qc * (THREADS * P);
  float qx[P], qy[P], qz[P], m[P];
  #pragma unroll
  for (int k = 0; k < P; ++k) {
    int qi = q0 + k * THREADS + tid;
    qx[k] = Qb[qi * 3 + 0];
    qy[k] = Qb[qi * 3 + 1];
    qz[k] = Qb[qi * 3 + 2];
    m[k] = 3.4e38f;
  }

  #pragma unroll 4
  for (int j = 0; j < JT; j += 2) {
    float4 t0 = sT[j];       // uniform address -> LDS broadcast
    float4 t1 = sT[j + 1];
    #pragma unroll
    for (int k = 0; k < P; ++k) {
      float r0 = fmaf(-qx[k], t0.x, t0.w);
      r0 = fmaf(-qy[k], t0.y, r0);
      r0 = fmaf(-qz[k], t0.z, r0);
      float r1 = fmaf(-qx[k], t1.x, t1.w);
      r1 = fmaf(-qy[k], t1.y, r1);
      r1 = fmaf(-qz[k], t1.z, r1);
      m[k] = fminf(fminf(r0, r1), m[k]);   // hope: v_min3_f32
    }
  }

  unsigned int* mb = minbuf + ((size_t)dir * BATCH + b) * NPTS + q0;
  #pragma unroll
  for (int k = 0; k < P; ++k) {
    atomicMin(mb + k * THREADS + tid, enc_f32(m[k]));
  }
}

__global__ __launch_bounds__(256) void chamfer_loss(
    const float* __restrict__ c1, const float* __restrict__ c2,
    const unsigned int* __restrict__ minbuf, float* __restrict__ partials) {
  int slot = blockIdx.x * 256 + threadIdx.x;
  int dir = slot >> 15;
  int b   = (slot >> 13) & 3;
  int i   = slot & (NPTS - 1);
  const float* Q = dir ? c2 : c1;
  const float* q = Q + ((size_t)b * NPTS + i) * 3;
  float x = q[0], y = q[1], z = q[2];
  float qq = x * x + y * y + z * z;
  float v = dec_f32(minbuf[slot]);
  float d2 = fmaf(2.0f, v, qq);   // = |q|^2 + |t*|^2 - 2 q.t*

  float s = d2;
  #pragma unroll
  for (int off = 32; off > 0; off >>= 1) s += __shfl_down(s, off, 64);
  __shared__ float wsum[4];
  if ((threadIdx.x & 63) == 0) wsum[threadIdx.x >> 6] = s;
  __syncthreads();
  if (threadIdx.x == 0)
    partials[blockIdx.x] = (wsum[0] + wsum[1]) + (wsum[2] + wsum[3]);
}

__global__ __launch_bounds__(256) void chamfer_final(
    const float* __restrict__ partials, float* __restrict__ out) {
  float s = partials[threadIdx.x];  // 256 partials, 256 threads
  #pragma unroll
  for (int off = 32; off > 0; off >>= 1) s += __shfl_down(s, off, 64);
  __shared__ float wsum[4];
  if ((threadIdx.x & 63) == 0) wsum[threadIdx.x >> 6] = s;
  __syncthreads();
  if (threadIdx.x == 0) out[0] = (wsum[0] + wsum[1]) + (wsum[2] + wsum[3]);
}

extern "C" void kernel_launch(void* const* d_in, const int* in_sizes, int n_in,
                              void* d_out, int out_size, void* d_ws, size_t ws_size,
                              hipStream_t stream) {
  const float* c1 = (const float*)d_in[0];
  const float* c2 = (const float*)d_in[1];
  float* out = (float*)d_out;

  unsigned int* minbuf = (unsigned int*)d_ws;                       // 65536 * 4 B
  float* partials = (float*)((char*)d_ws + (size_t)NSLOTS * 4);     // 256 * 4 B

  init_min<<<NSLOTS / 256, 256, 0, stream>>>(minbuf);
  chamfer_min<<<2 * BATCH * 4 * NJC, THREADS, 0, stream>>>(c1, c2, minbuf);
  chamfer_loss<<<NSLOTS / 256, 256, 0, stream>>>(c1, c2, minbuf, partials);
  chamfer_final<<<1, 256, 0, stream>>>(partials, out);
}